// Round 5
// baseline (111.788 us; speedup 1.0000x reference)
//
#include <hip/hip_runtime.h>
#include <stdint.h>

// Problem constants (from reference setup_inputs)
#define BATCH 4096
#define ISZ   512
#define OSZ   512
#define KDIM  4096           // contraction dim: k = i*8 + d

// GEMM tiling
#define TM 128
#define TN 128
#define BK 64
#define SPLITK 4

typedef __bf16 bf16x8 __attribute__((ext_vector_type(8)));
typedef float  f32x4  __attribute__((ext_vector_type(4)));

__device__ __forceinline__ unsigned short f2bf(float f) {
    uint32_t u = __float_as_uint(f);
    u = (u + 0x7FFFu + ((u >> 16) & 1u)) >> 16;
    return (unsigned short)u;
}

// flat fp32 -> bf16 convert (coef already k-contiguous: [O][I][D] -> [O][K])
__global__ __launch_bounds__(256) void convert_bf16(
    const float* __restrict__ src, unsigned short* __restrict__ dst, int n4)
{
    int idx = blockIdx.x * 256 + threadIdx.x;
    if (idx >= n4) return;
    float4 v = reinterpret_cast<const float4*>(src)[idx];
    uint2 o;
    o.x = (uint32_t)f2bf(v.x) | ((uint32_t)f2bf(v.y) << 16);
    o.y = (uint32_t)f2bf(v.z) | ((uint32_t)f2bf(v.w) << 16);
    reinterpret_cast<uint2*>(dst)[idx] = o;
}

// One jacobi8 evaluation -> exactly one MFMA A-fragment (bf16x8).
// A-frag layout (verified R1-R4 via LDS path): lane l holds
// A[m=l&15][k=(l>>4)*8 + j], j=0..7; with k=i*8+d those 8 k are the 8
// Jacobi orders of a single i -> compute them straight into registers.
__device__ __forceinline__ bf16x8 jac8(float xv) {
    // tanh(x) = 1 - 2/(exp(2x)+1); v_exp+v_rcp err ~1e-6 << bf16 ulp
    float e  = __expf(2.0f * xv);
    float t  = 1.0f - 2.0f * __builtin_amdgcn_rcpf(e + 1.0f);
    float p0 = 1.0f;
    float p1 = 2.0f * t;
    float p2 = (1.875f     * t) * p1 - 0.75f       * p0;
    float p3 = (1.8666667f * t) * p2 - 0.8f        * p1;
    float p4 = (1.875f     * t) * p3 - 0.83333333f * p2;
    float p5 = (1.8857143f * t) * p4 - 0.85714287f * p3;
    float p6 = (1.8958333f * t) * p5 - 0.875f      * p4;
    float p7 = (1.9047619f * t) * p6 - 0.88888889f * p5;
    bf16x8 r;
    r[0] = (__bf16)p0; r[1] = (__bf16)p1; r[2] = (__bf16)p2; r[3] = (__bf16)p3;
    r[4] = (__bf16)p4; r[5] = (__bf16)p5; r[6] = (__bf16)p6; r[7] = (__bf16)p7;
    return r;
}

// Fused Jacobi + GEMM, split-K partials with plain stores (R3: atomics cost
// ~50us TCC serialization; R4: plain-store+reduce wins).
// Cp[z][M][N] = A[M][Kz] * Bm[N][Kz]^T, A[m][i*8+d] = P_d(tanh(x[m][i])).
// R5 changes vs R4:
//  - A never touches LDS: each lane computes its A-fragments in-register
//    (jac8 above). Halves LDS read traffic and removes the A-store barrier dep.
//  - B double-buffered with prefetch distance 1: loads for tile k+1 are
//    issued at iter start, so the end-of-iter barrier's vmcnt(0) drain waits
//    on loads that had the whole compute phase (~1500 cy) in flight.
// 128x128 block tile, BK=64, 256 threads = 4 waves (2x2), wave tile 64x64
// via 4x4 of mfma_f32_16x16x32_bf16. B LDS: 16B chunks, XOR swizzle slot =
// row*8 + (c ^ (row&7)) -> SQ_LDS_BANK_CONFLICT == 0 measured R2-R4; keeps
// global_load_lds wave-uniform-base + lane*16 dest contract (swizzle applied
// to per-lane *source* address).
__global__ __launch_bounds__(256, 2) void gemm_fused(
    const float* __restrict__ X,            // [BATCH][ISZ] fp32
    const unsigned short* __restrict__ Bm,  // [OSZ][KDIM] bf16 bits
    float* __restrict__ Cp, int M, int N, int K)
{
    __shared__ __align__(16) unsigned short Bs[2][TN * BK];   // 2 x 16 KB

    const int tid  = threadIdx.x;
    const int wave = tid >> 6;
    const int lane = tid & 63;
    const int wm   = (wave >> 1) * 64;      // wave row offset in tile
    const int wn   = (wave & 1) * 64;       // wave col offset in tile

    const int    m0    = blockIdx.x * TM;
    const size_t baseB = (size_t)blockIdx.y * TN * K;
    const int kper = K / SPLITK;            // 1024
    const int kbeg = blockIdx.z * kper;
    const int niter = kper / BK;            // 16

    f32x4 acc[4][4] = {};

    const int mrow = lane & 15;             // m within 16x16 tile
    const int kc   = lane >> 4;             // 16B-chunk column offset within k

    // B staging: 128x64 bf16 = 16 KB = 1024 chunks of 16B; 256 thr x 4 its.
    auto stageB = [&](int k0, int buf) {
        #pragma unroll
        for (int it = 0; it < 4; ++it) {
            int s    = it * 256 + tid;
            int row  = s >> 3;
            int csrc = (s & 7) ^ (row & 7);
            const unsigned short* gB = Bm + baseB + (size_t)row * K + k0 + csrc * 8;
            unsigned short* lB = &Bs[buf][0] + (size_t)(it * 256 + wave * 64) * 8;
            __builtin_amdgcn_global_load_lds(
                (const __attribute__((address_space(1))) uint32_t*)gB,
                (__attribute__((address_space(3))) uint32_t*)lB, 16, 0, 0);
        }
    };

    stageB(kbeg, 0);
    __syncthreads();

    for (int kt = 0; kt < niter; ++kt) {
        const int k0 = kbeg + kt * BK;
        const int p  = kt & 1;
        if (kt + 1 < niter) stageB(k0 + BK, 1 - p);

        // ---- A fragments in-register: 8 jacobi evals per lane ----
        const int i0 = (k0 >> 3) + kc;      // i for ks=0 quad
        bf16x8 aF0[4], aF1[4];
        #pragma unroll
        for (int mi = 0; mi < 4; ++mi) {
            const float* xp = X + (size_t)(m0 + wm + mi * 16 + mrow) * ISZ + i0;
            aF0[mi] = jac8(xp[0]);          // ks=0  -> i = i0
            aF1[mi] = jac8(xp[4]);          // ks=32 -> i = i0+4
        }

        // ---- B fragments from LDS buf p + MFMA ----
        const unsigned short* Bp = &Bs[p][0];
        #pragma unroll
        for (int ks = 0; ks < BK; ks += 32) {
            bf16x8 bF[4];
            const int cbase = (ks >> 3) + kc;
            #pragma unroll
            for (int ni = 0; ni < 4; ++ni) {
                int r = wn + ni * 16 + mrow;
                int slot = r * 8 + (cbase ^ (r & 7));
                bF[ni] = *reinterpret_cast<const bf16x8*>(Bp + (size_t)slot * 8);
            }
            #pragma unroll
            for (int mi = 0; mi < 4; ++mi)
                #pragma unroll
                for (int ni = 0; ni < 4; ++ni)
                    acc[mi][ni] = __builtin_amdgcn_mfma_f32_16x16x32_bf16(
                        ks ? aF1[mi] : aF0[mi], bF[ni], acc[mi][ni], 0, 0, 0);
        }
        __syncthreads();   // completes buf[1-p] loads; fences buf[p] reuse
    }

    // plain stores of split-K partials (no atomics)
    // C/D layout (m89-verified): col = lane&15, row = (lane>>4)*4 + r
    float* Cz = Cp + (size_t)blockIdx.z * M * N;
    const int orow = blockIdx.x * TM + wm + (lane >> 4) * 4;
    const int ocol = blockIdx.y * TN + wn + (lane & 15);
    #pragma unroll
    for (int mi = 0; mi < 4; ++mi)
        #pragma unroll
        for (int ni = 0; ni < 4; ++ni)
            #pragma unroll
            for (int r = 0; r < 4; ++r)
                Cz[(size_t)(orow + mi * 16 + r) * N + ocol + ni * 16] =
                    acc[mi][ni][r];
}

// out = sum over SPLITK partials, float4-vectorized
__global__ __launch_bounds__(256) void reduce_k(
    const float* __restrict__ part, float* __restrict__ out, int n4)
{
    int idx = blockIdx.x * 256 + threadIdx.x;
    if (idx >= n4) return;
    const float4* p = reinterpret_cast<const float4*>(part);
    float4 a = p[idx];
    #pragma unroll
    for (int z = 1; z < SPLITK; ++z) {
        float4 b = p[(size_t)z * n4 + idx];
        a.x += b.x; a.y += b.y; a.z += b.z; a.w += b.w;
    }
    reinterpret_cast<float4*>(out)[idx] = a;
}

extern "C" void kernel_launch(void* const* d_in, const int* in_sizes, int n_in,
                              void* d_out, int out_size, void* d_ws, size_t ws_size,
                              hipStream_t stream)
{
    const float* x    = (const float*)d_in[0];   // [4096][512]
    const float* coef = (const float*)d_in[1];   // [512][512][8]
    float* out = (float*)d_out;                  // [4096][512]

    // workspace: partials fp32 [SPLITK][4096][512] (32 MB) + coef bf16 (4 MB)
    float* part = (float*)d_ws;
    unsigned short* coefb =
        (unsigned short*)(part + (size_t)SPLITK * BATCH * OSZ);

    int n4c = (OSZ * KDIM) / 4;                  // 524,288
    convert_bf16<<<(n4c + 255) / 256, 256, 0, stream>>>(coef, coefb, n4c);

    dim3 grid(BATCH / TM, OSZ / TN, SPLITK);     // 32 x 4 x 4 = 512 blocks
    gemm_fused<<<grid, 256, 0, stream>>>(x, coefb, part, BATCH, OSZ, KDIM);

    int n4r = (BATCH * OSZ) / 4;                 // 524,288
    reduce_k<<<(n4r + 255) / 256, 256, 0, stream>>>(part, out, n4r);
}

// Round 6
// 98.793 us; speedup vs baseline: 1.1315x; 1.1315x over previous
//
#include <hip/hip_runtime.h>
#include <stdint.h>

// Problem constants (from reference setup_inputs)
#define BATCH 4096
#define ISZ   512
#define OSZ   512
#define KDIM  4096           // contraction dim: k = i*8 + d

// GEMM tiling
#define TM 128
#define TN 128
#define BK 64
#define SPLITK 4

typedef __bf16 bf16x8 __attribute__((ext_vector_type(8)));
typedef float  f32x4  __attribute__((ext_vector_type(4)));

__device__ __forceinline__ unsigned short f2bf(float f) {
    uint32_t u = __float_as_uint(f);
    u = (u + 0x7FFFu + ((u >> 16) & 1u)) >> 16;
    return (unsigned short)u;
}

// flat fp32 -> bf16 convert (coef already k-contiguous: [O][I][D] -> [O][K])
__global__ __launch_bounds__(256) void convert_bf16(
    const float* __restrict__ src, unsigned short* __restrict__ dst, int n4)
{
    int idx = blockIdx.x * 256 + threadIdx.x;
    if (idx >= n4) return;
    float4 v = reinterpret_cast<const float4*>(src)[idx];
    uint2 o;
    o.x = (uint32_t)f2bf(v.x) | ((uint32_t)f2bf(v.y) << 16);
    o.y = (uint32_t)f2bf(v.z) | ((uint32_t)f2bf(v.w) << 16);
    reinterpret_cast<uint2*>(dst)[idx] = o;
}

// Fused Jacobi + GEMM, bf16 split-K partials with plain stores.
// Structure history: R3 atomics = ~50us TCC serialization (removed);
// R5 in-register A = 2x duplicated VALU + dependent jac->MFMA chain
// (reverted). R6 = R4's shared-A-via-LDS (1024 evals/block-iter, 4/thread,
// shared by all 4 waves) + R5's double-buffer prefetch-distance-1 on BOTH
// A and B: next tile's staging is issued before this tile's MFMA phase, so
// the end-of-iter barrier drains loads/writes that had ~1.5K cy to fly.
// 128x128 block tile, BK=64, 256 threads = 4 waves (2x2), wave tile 64x64
// via 4x4 of mfma_f32_16x16x32_bf16 (layout verified R1-R5).
// LDS: 16B chunks, XOR swizzle slot = row*8 + (c ^ (row&7)) ->
// SQ_LDS_BANK_CONFLICT == 0 measured R2-R5. B keeps global_load_lds's
// wave-uniform-base + lane*16 dest contract (swizzle on per-lane source
// address); A is ds_write_b128 (per-lane scatter fine), same slot map.
__global__ __launch_bounds__(256, 2) void gemm_fused(
    const float* __restrict__ X,            // [BATCH][ISZ] fp32
    const unsigned short* __restrict__ Bm,  // [OSZ][KDIM] bf16 bits
    unsigned short* __restrict__ Cp,        // [SPLITK][M][N] bf16 partials
    int M, int N, int K)
{
    __shared__ __align__(16) unsigned short As[2][TM * BK];   // 2 x 16 KB
    __shared__ __align__(16) unsigned short Bs[2][TN * BK];   // 2 x 16 KB

    const int tid  = threadIdx.x;
    const int wave = tid >> 6;
    const int lane = tid & 63;
    const int wm   = (wave >> 1) * 64;      // wave row offset in tile
    const int wn   = (wave & 1) * 64;       // wave col offset in tile

    const int    m0    = blockIdx.x * TM;
    const size_t baseB = (size_t)blockIdx.y * TN * K;
    const int kper  = K / SPLITK;           // 1024
    const int kbeg  = blockIdx.z * kper;
    const int niter = kper / BK;            // 16

    f32x4 acc[4][4] = {};

    const int mrow = lane & 15;             // m within 16x16 tile
    const int kc   = lane >> 4;             // 16B-chunk column offset within k

    // A-compute assignment: thread t -> row xr = t>>1, chunk cols xc..xc+3
    const int xr = tid >> 1;
    const int xc = (tid & 1) * 4;

    // B staging: 128x64 bf16 = 16 KB = 1024 chunks of 16B; 256 thr x 4 its.
    auto stageB = [&](int k0, int buf) {
        #pragma unroll
        for (int it = 0; it < 4; ++it) {
            int s    = it * 256 + tid;
            int row  = s >> 3;
            int csrc = (s & 7) ^ (row & 7);
            const unsigned short* gB = Bm + baseB + (size_t)row * K + k0 + csrc * 8;
            unsigned short* lB = &Bs[buf][0] + (size_t)(it * 256 + wave * 64) * 8;
            __builtin_amdgcn_global_load_lds(
                (const __attribute__((address_space(1))) uint32_t*)gB,
                (__attribute__((address_space(3))) uint32_t*)lB, 16, 0, 0);
        }
    };

    // A staging: jacobi8(tanh(x)) for chunk (xr, xc..xc+3) -> As[buf]
    auto stageA = [&](int k0, int buf) {
        const int i0 = k0 >> 3;
        float4 xv = *reinterpret_cast<const float4*>(
            X + (size_t)(m0 + xr) * ISZ + i0 + xc);
        const float xs[4] = {xv.x, xv.y, xv.z, xv.w};
        #pragma unroll
        for (int j = 0; j < 4; ++j) {
            // tanh(x) = 1 - 2/(exp(2x)+1); err ~1e-6 << bf16 ulp
            float e  = __expf(2.0f * xs[j]);
            float t  = 1.0f - 2.0f * __builtin_amdgcn_rcpf(e + 1.0f);
            float p0 = 1.0f;
            float p1 = 2.0f * t;
            float p2 = (1.875f     * t) * p1 - 0.75f       * p0;
            float p3 = (1.8666667f * t) * p2 - 0.8f        * p1;
            float p4 = (1.875f     * t) * p3 - 0.83333333f * p2;
            float p5 = (1.8857143f * t) * p4 - 0.85714287f * p3;
            float p6 = (1.8958333f * t) * p5 - 0.875f      * p4;
            float p7 = (1.9047619f * t) * p6 - 0.88888889f * p5;
            uint4 o;
            o.x = (uint32_t)f2bf(p0) | ((uint32_t)f2bf(p1) << 16);
            o.y = (uint32_t)f2bf(p2) | ((uint32_t)f2bf(p3) << 16);
            o.z = (uint32_t)f2bf(p4) | ((uint32_t)f2bf(p5) << 16);
            o.w = (uint32_t)f2bf(p6) | ((uint32_t)f2bf(p7) << 16);
            int slot = xr * 8 + ((xc + j) ^ (xr & 7));
            *reinterpret_cast<uint4*>(&As[buf][0] + (size_t)slot * 8) = o;
        }
    };

    stageB(kbeg, 0);
    stageA(kbeg, 0);
    __syncthreads();

    for (int kt = 0; kt < niter; ++kt) {
        const int k0 = kbeg + kt * BK;
        const int p  = kt & 1;
        if (kt + 1 < niter) {
            stageB(k0 + BK, 1 - p);     // async loads fly through MFMA phase
            stageA(k0 + BK, 1 - p);     // VALU overlaps MFMA (m114)
        }

        const unsigned short* Ap = &As[p][0];
        const unsigned short* Bp = &Bs[p][0];
        #pragma unroll
        for (int ks = 0; ks < BK; ks += 32) {
            bf16x8 aF[4], bF[4];
            const int cbase = (ks >> 3) + kc;
            #pragma unroll
            for (int mi = 0; mi < 4; ++mi) {
                int r = wm + mi * 16 + mrow;
                int slot = r * 8 + (cbase ^ (r & 7));
                aF[mi] = *reinterpret_cast<const bf16x8*>(Ap + (size_t)slot * 8);
            }
            #pragma unroll
            for (int ni = 0; ni < 4; ++ni) {
                int r = wn + ni * 16 + mrow;
                int slot = r * 8 + (cbase ^ (r & 7));
                bF[ni] = *reinterpret_cast<const bf16x8*>(Bp + (size_t)slot * 8);
            }
            #pragma unroll
            for (int mi = 0; mi < 4; ++mi)
                #pragma unroll
                for (int ni = 0; ni < 4; ++ni)
                    acc[mi][ni] = __builtin_amdgcn_mfma_f32_16x16x32_bf16(
                        aF[mi], bF[ni], acc[mi][ni], 0, 0, 0);
        }
        __syncthreads();   // completes buf[1-p] stage; fences buf[p] reuse
    }

    // bf16 partials, plain stores (no atomics).
    // C/D layout (m89-verified): col = lane&15, row = (lane>>4)*4 + r
    unsigned short* Cz = Cp + (size_t)blockIdx.z * M * N;
    const int orow = blockIdx.x * TM + wm + (lane >> 4) * 4;
    const int ocol = blockIdx.y * TN + wn + (lane & 15);
    #pragma unroll
    for (int mi = 0; mi < 4; ++mi)
        #pragma unroll
        for (int ni = 0; ni < 4; ++ni)
            #pragma unroll
            for (int r = 0; r < 4; ++r)
                Cz[(size_t)(orow + mi * 16 + r) * N + ocol + ni * 16] =
                    f2bf(acc[mi][ni][r]);
}

// out = sum over SPLITK bf16 partials (fp32 accumulate), 4 outputs/thread
__global__ __launch_bounds__(256) void reduce_k(
    const unsigned short* __restrict__ part, float* __restrict__ out, int n4)
{
    int idx = blockIdx.x * 256 + threadIdx.x;
    if (idx >= n4) return;
    const uint2* p = reinterpret_cast<const uint2*>(part);   // 4 bf16 / uint2
    float s0 = 0.f, s1 = 0.f, s2 = 0.f, s3 = 0.f;
    #pragma unroll
    for (int z = 0; z < SPLITK; ++z) {
        uint2 v = p[(size_t)z * n4 + idx];
        s0 += __uint_as_float((v.x & 0xFFFFu) << 16);
        s1 += __uint_as_float(v.x & 0xFFFF0000u);
        s2 += __uint_as_float((v.y & 0xFFFFu) << 16);
        s3 += __uint_as_float(v.y & 0xFFFF0000u);
    }
    float4 o = {s0, s1, s2, s3};
    reinterpret_cast<float4*>(out)[idx] = o;
}

extern "C" void kernel_launch(void* const* d_in, const int* in_sizes, int n_in,
                              void* d_out, int out_size, void* d_ws, size_t ws_size,
                              hipStream_t stream)
{
    const float* x    = (const float*)d_in[0];   // [4096][512]
    const float* coef = (const float*)d_in[1];   // [512][512][8]
    float* out = (float*)d_out;                  // [4096][512]

    // workspace: bf16 partials [SPLITK][4096][512] (16 MB) + coef bf16 (4 MB)
    unsigned short* part  = (unsigned short*)d_ws;
    unsigned short* coefb = part + (size_t)SPLITK * BATCH * OSZ;

    int n4c = (OSZ * KDIM) / 4;                  // 524,288
    convert_bf16<<<(n4c + 255) / 256, 256, 0, stream>>>(coef, coefb, n4c);

    dim3 grid(BATCH / TM, OSZ / TN, SPLITK);     // 32 x 4 x 4 = 512 blocks
    gemm_fused<<<grid, 256, 0, stream>>>(x, coefb, part, BATCH, OSZ, KDIM);

    int n4r = (BATCH * OSZ) / 4;                 // 524,288
    reduce_k<<<(n4r + 255) / 256, 256, 0, stream>>>(part, out, n4r);
}